// Round 17
// baseline (471.035 us; speedup 1.0000x reference)
//
#include <hip/hip_runtime.h>
#include <hip/hip_fp16.h>

#define BLOCK 256
#define PAD 16        // one counter per 64B cache line
#define SUBCAP 512    // staging capacity per (bucket, xcd)
#define OVCAP 4096    // overflow capacity per bucket
#define BUFCAP 4352   // binB LDS record capacity

typedef _Float16 h2v __attribute__((ext_vector_type(2)));

#if defined(__has_builtin) && __has_builtin(__builtin_amdgcn_sched_barrier)
#define SCHED_FENCE() __builtin_amdgcn_sched_barrier(0)
#else
#define SCHED_FENCE()
#endif

// ---------------- helpers ----------------
__device__ inline void st4f(__half* p, float4 v) {
    __half2 a = __floats2half2_rn(v.x, v.y);
    __half2 b = __floats2half2_rn(v.z, v.w);
    uint2 u;
    u.x = *reinterpret_cast<unsigned*>(&a);
    u.y = *reinterpret_cast<unsigned*>(&b);
    *(uint2*)p = u;
}
__device__ inline void st4f(float* p, float4 v) { *(float4*)p = v; }
__device__ inline void st8f(float* p, const float f[8]) {
    *(float4*)p       = make_float4(f[0], f[1], f[2], f[3]);
    *(float4*)(p + 4) = make_float4(f[4], f[5], f[6], f[7]);
}
__device__ inline void st8f(__half* p, const float f[8]) {
    union { __half2 h[4]; float4 v; } u;
    u.h[0] = __floats2half2_rn(f[0], f[1]);
    u.h[1] = __floats2half2_rn(f[2], f[3]);
    u.h[2] = __floats2half2_rn(f[4], f[5]);
    u.h[3] = __floats2half2_rn(f[6], f[7]);
    *(float4*)p = u.v;
}
__device__ inline void ld2v(const __half* p, float* f) {
    float2 v = __half22float2(*(const __half2*)p); f[0] = v.x; f[1] = v.y;
}
__device__ inline void ld8v(const __half* p, float* f) {
    float4 r = *(const float4*)p;
    const __half2* h = (const __half2*)&r;
#pragma unroll
    for (int j = 0; j < 4; ++j) {
        float2 fj = __half22float2(h[j]);
        f[2*j] = fj.x; f[2*j+1] = fj.y;
    }
}
__device__ inline float4 ld4f(const float* p) { return *(const float4*)p; }
__device__ inline float edgeW(int2 er) {
    return __half2float(__ushort_as_half((unsigned short)(er.y & 0xffff)));
}
__device__ inline h2v packh2(float a, float b) {
    h2v r; r.x = (_Float16)a; r.y = (_Float16)b; return r;
}

// ---------------- binA: 4 edges/thread, phase-batched for MLP ----------------
// XCC_ID is a locality hint only; binB drains all sub-regions + overflow, so
// any xcc value is correct. degO atomics are fire-and-forget (no return).
__global__ void binA_kernel(const int* __restrict__ src, const int* __restrict__ dst,
                            const float* __restrict__ efet,
                            int* __restrict__ degO_x,
                            int* __restrict__ scur, int* __restrict__ ovcur,
                            int2* __restrict__ staging, int2* __restrict__ overflow,
                            int N, int E, int T) {
    int t0 = blockIdx.x * blockDim.x + threadIdx.x;
    if (t0 >= T) return;
    int xcc = __builtin_amdgcn_s_getreg(63508) & 7;   // hwreg(XCC_ID,0,32)

    int e[4], s[4], d[4];
    float w[4];
    int nv = 0;
#pragma unroll
    for (int q = 0; q < 4; ++q) {
        e[q] = t0 + q * T;
        if (e[q] < E) nv = q + 1;
    }
#pragma unroll
    for (int q = 0; q < 4; ++q) if (q < nv) { s[q] = src[e[q]]; }
#pragma unroll
    for (int q = 0; q < 4; ++q) if (q < nv) { d[q] = dst[e[q]]; }
#pragma unroll
    for (int q = 0; q < 4; ++q) if (q < nv) { w[q] = efet[e[q]]; }
    SCHED_FENCE();
#pragma unroll
    for (int q = 0; q < 4; ++q) if (q < nv)
        atomicAdd(&degO_x[(size_t)xcc * N + s[q]], 1);   // no return -> fire & forget
    SCHED_FENCE();
    int p[4], slot[4];
#pragma unroll
    for (int q = 0; q < 4; ++q) if (q < nv) {
        slot[q] = (d[q] >> 7) * 8 + xcc;
        p[q] = atomicAdd(&scur[slot[q] * PAD], 1);
    }
    SCHED_FENCE();
#pragma unroll
    for (int q = 0; q < 4; ++q) if (q < nv) {
        int2 rec;
        rec.x = s[q];
        rec.y = (int)__half_as_ushort(__float2half(w[q])) | ((d[q] & 127) << 16);
        if (p[q] < SUBCAP) {
            staging[(size_t)slot[q] * SUBCAP + p[q]] = rec;
        } else {
            int b = d[q] >> 7;
            int oq = atomicAdd(&ovcur[b * PAD], 1);
            if (oq < OVCAP) overflow[(size_t)b * OVCAP + oq] = rec;
        }
    }
}

// ---------------- binB: bucket drain -> LDS -> count/scan/ticket -> rowSpan+edges
//                   + normO/xh conversion for the bucket's nodes ----------------
__global__ __launch_bounds__(256) void binB_kernel(
    const int* __restrict__ scur, const int* __restrict__ ovcur,
    const int2* __restrict__ staging, const int2* __restrict__ overflow,
    int* __restrict__ gcur, int2* __restrict__ rowSpan, float* __restrict__ normI,
    int2* __restrict__ edges,
    const int* __restrict__ degO_x, const float* __restrict__ x,
    __half* __restrict__ xh, float* __restrict__ normO, int N) {
    __shared__ int2 buf[BUFCAP];
    __shared__ int cnt[128];
    __shared__ int rs[128];
    __shared__ int cur[128];
    __shared__ float nO[128];
    __shared__ int base;
    int b = blockIdx.x;
    int v0 = b << 7;
    int t = threadIdx.x;
    int nn = N - v0; if (nn > 128) nn = 128;
    if (t < 128) cnt[t] = 0;

    // region offsets (computed identically by all threads)
    int offs[8], acc = 0;
#pragma unroll
    for (int r = 0; r < 8; ++r) {
        int c = scur[(b * 8 + r) * PAD];
        if (c > SUBCAP) c = SUBCAP;
        offs[r] = acc; acc += c;
    }
    int oc = ovcur[b * PAD];
    if (oc > OVCAP) oc = OVCAP;
    int total = acc + oc;
    if (total > BUFCAP) total = BUFCAP;
    __syncthreads();

    // drain staging + overflow into LDS
#pragma unroll
    for (int r = 0; r < 8; ++r) {
        int c = (r < 7 ? offs[r + 1] : acc) - offs[r];
        const int2* reg = staging + (size_t)(b * 8 + r) * SUBCAP;
        for (int i = t; i < c; i += 256) {
            int o = offs[r] + i;
            if (o < BUFCAP) buf[o] = reg[i];
        }
    }
    {
        const int2* reg = overflow + (size_t)b * OVCAP;
        for (int i = t; i < oc; i += 256) {
            int o = acc + i;
            if (o < BUFCAP) buf[o] = reg[i];
        }
    }
    __syncthreads();

    // count per-node
    for (int i = t; i < total; i += 256)
        atomicAdd(&cnt[(buf[i].y >> 16) & 127], 1);
    __syncthreads();

    if (t == 0) {
        base = atomicAdd(gcur, total);
        int a2 = 0;
        for (int k = 0; k < 128; ++k) { rs[k] = a2; a2 += cnt[k]; }
    }
    __syncthreads();

    if (t < 128) {
        cur[t] = 0;
        int v = v0 + t;
        if (v < N) {
            int2 sp;
            sp.x = base + rs[t];
            sp.y = sp.x + cnt[t];
            rowSpan[v] = sp;
            normI[v] = rsqrtf(fmaxf((float)cnt[t], 1.0f));
            int dsum = 0;
#pragma unroll
            for (int k = 0; k < 8; ++k) dsum += degO_x[(size_t)k * N + v];
            float wv = rsqrtf(fmaxf((float)dsum, 1.0f));
            nO[t] = wv;
            normO[v] = wv;
        }
    }
    __syncthreads();

    // scatter LDS -> contiguous bucket span of edges
    for (int i = t; i < total; i += 256) {
        int2 rec = buf[i];
        int dl = (rec.y >> 16) & 127;
        int lp = atomicAdd(&cur[dl], 1);
        edges[base + rs[dl] + lp] = rec;
    }

    // x -> fp16 with normO folded, for this bucket's nodes
    for (int i = t; i < nn * 4; i += 256) {
        int vl = i >> 2, c = (i & 3) * 4;
        int v = v0 + vl;
        float4 f = ld4f(x + (size_t)v * 16 + c);
        float wv = nO[vl];
        f.x *= wv; f.y *= wv; f.z *= wv; f.w *= wv;
        st4f(xh + (size_t)v * 16 + c, f);
    }
}

// ---------------- CSR gather-agg, 8 cols/thread, sched-fenced batched loads ---------
template <int D>
__global__ __launch_bounds__(256) void agg8_kernel(
    const __half* __restrict__ in, __half* __restrict__ out,
    const int2* __restrict__ rowSpan, const int2* __restrict__ edges,
    int useW,
    const float* __restrict__ dstScale,   // null -> skip scale+bias
    const float* __restrict__ bias,
    int N, int relu) {
    constexpr int TPN = D / 8;
    int gid = blockIdx.x * blockDim.x + threadIdx.x;
    int v = gid / TPN;
    int c8 = (gid % TPN) * 8;
    if (v >= N) return;
    int2 sp = rowSpan[v];
    int beg = sp.x, end = sp.y;
    float a[8];
#pragma unroll
    for (int k = 0; k < 8; ++k) a[k] = 0.f;
    const __half* base = in + c8;

    int j = beg;
    for (; j + 8 <= end; j += 8) {
        int2 er[8];
#pragma unroll
        for (int q = 0; q < 8; ++q) er[q] = edges[j + q];
        SCHED_FENCE();
        float4 raw[8];
#pragma unroll
        for (int q = 0; q < 8; ++q) raw[q] = *(const float4*)(base + (size_t)er[q].x * D);
        SCHED_FENCE();
#pragma unroll
        for (int q = 0; q < 8; ++q) {
            float w = useW ? edgeW(er[q]) : 1.f;
            const __half2* h = (const __half2*)&raw[q];
#pragma unroll
            for (int p = 0; p < 4; ++p) {
                float2 fj = __half22float2(h[p]);
                a[2*p]   += fj.x * w;
                a[2*p+1] += fj.y * w;
            }
        }
    }
    if (j + 4 <= end) {
        int2 er[4];
#pragma unroll
        for (int q = 0; q < 4; ++q) er[q] = edges[j + q];
        SCHED_FENCE();
        float4 raw[4];
#pragma unroll
        for (int q = 0; q < 4; ++q) raw[q] = *(const float4*)(base + (size_t)er[q].x * D);
        SCHED_FENCE();
#pragma unroll
        for (int q = 0; q < 4; ++q) {
            float w = useW ? edgeW(er[q]) : 1.f;
            const __half2* h = (const __half2*)&raw[q];
#pragma unroll
            for (int p = 0; p < 4; ++p) {
                float2 fj = __half22float2(h[p]);
                a[2*p]   += fj.x * w;
                a[2*p+1] += fj.y * w;
            }
        }
        j += 4;
    }
    for (; j < end; ++j) {
        int2 er = edges[j];
        float w = useW ? edgeW(er) : 1.f;
        float xv[8];
        ld8v(base + (size_t)er.x * D, xv);
#pragma unroll
        for (int k = 0; k < 8; ++k) a[k] += xv[k] * w;
    }
    if (dstScale) {
        float sc = dstScale[v];
#pragma unroll
        for (int k = 0; k < 8; ++k) a[k] = a[k] * sc + bias[c8 + k];
    }
    if (relu) {
#pragma unroll
        for (int k = 0; k < 8; ++k) a[k] = fmaxf(a[k], 0.f);
    }
    st8f(out + (size_t)v * D + c8, a);
}

// ---------------- gc32 fused with 32->4 GEMM (W5) ----------------
__global__ __launch_bounds__(256) void gc32_fused(
    const __half* __restrict__ in, float* __restrict__ t5,
    const int2* __restrict__ rowSpan, const int2* __restrict__ edges,
    const float* __restrict__ normI, const float* __restrict__ b4,
    const float* __restrict__ normO, const float* __restrict__ W5,
    int N) {
    int gid = blockIdx.x * blockDim.x + threadIdx.x;
    int v = gid >> 2;
    int q = gid & 3;
    int c8 = q * 8;
    if (v >= N) return;
    int2 sp = rowSpan[v];
    int beg = sp.x, end = sp.y;
    float a[8];
#pragma unroll
    for (int k = 0; k < 8; ++k) a[k] = 0.f;
    const __half* base = in + c8;

    int j = beg;
    for (; j + 8 <= end; j += 8) {
        int2 er[8];
#pragma unroll
        for (int p = 0; p < 8; ++p) er[p] = edges[j + p];
        SCHED_FENCE();
        float4 raw[8];
#pragma unroll
        for (int p = 0; p < 8; ++p) raw[p] = *(const float4*)(base + (size_t)er[p].x * 32);
        SCHED_FENCE();
#pragma unroll
        for (int p = 0; p < 8; ++p) {
            const __half2* h = (const __half2*)&raw[p];
#pragma unroll
            for (int s = 0; s < 4; ++s) {
                float2 fj = __half22float2(h[s]);
                a[2*s]   += fj.x;
                a[2*s+1] += fj.y;
            }
        }
    }
    for (; j < end; ++j) {
        int2 er = edges[j];
        float xv[8];
        ld8v(base + (size_t)er.x * 32, xv);
#pragma unroll
        for (int k = 0; k < 8; ++k) a[k] += xv[k];
    }
    float sc = normI[v];
#pragma unroll
    for (int k = 0; k < 8; ++k) a[k] = fmaxf(a[k] * sc + b4[c8 + k], 0.f);

    float p4[4] = {0.f, 0.f, 0.f, 0.f};
#pragma unroll
    for (int k = 0; k < 8; ++k) {
        float4 wr = ld4f(W5 + (size_t)(c8 + k) * 4);
        p4[0] += a[k] * wr.x; p4[1] += a[k] * wr.y;
        p4[2] += a[k] * wr.z; p4[3] += a[k] * wr.w;
    }
#pragma unroll
    for (int c = 0; c < 4; ++c) {
        p4[c] += __shfl_xor(p4[c], 1);
        p4[c] += __shfl_xor(p4[c], 2);
    }
    if (q == 0) {
        float no = normO[v];
        st4f(t5 + (size_t)v * 4, make_float4(p4[0]*no, p4[1]*no, p4[2]*no, p4[3]*no));
    }
}

// ---------------- final agg: D=4, fp32, batched loads ----------------
__global__ void agg4_kernel(const float* __restrict__ in, float* __restrict__ out,
                            const int2* __restrict__ rowSpan, const int2* __restrict__ edges,
                            const float* __restrict__ dstScale, const float* __restrict__ bias,
                            int N) {
    int v = blockIdx.x * blockDim.x + threadIdx.x;
    if (v >= N) return;
    int2 sp = rowSpan[v];
    int beg = sp.x, end = sp.y;
    float ax = 0.f, ay = 0.f, az = 0.f, aw = 0.f;
    int j = beg;
    for (; j + 4 <= end; j += 4) {
        int2 er[4];
#pragma unroll
        for (int q = 0; q < 4; ++q) er[q] = edges[j + q];
        SCHED_FENCE();
        float4 raw[4];
#pragma unroll
        for (int q = 0; q < 4; ++q) raw[q] = ld4f(in + (size_t)er[q].x * 4);
        SCHED_FENCE();
#pragma unroll
        for (int q = 0; q < 4; ++q) {
            ax += raw[q].x; ay += raw[q].y; az += raw[q].z; aw += raw[q].w;
        }
    }
    for (; j < end; ++j) {
        float4 val = ld4f(in + (size_t)edges[j].x * 4);
        ax += val.x; ay += val.y; az += val.z; aw += val.w;
    }
    float sc = dstScale[v];
    ax = ax * sc + bias[0];
    ay = ay * sc + bias[1];
    az = az * sc + bias[2];
    aw = aw * sc + bias[3];
    st4f(out + (size_t)v * 4, make_float4(ax, ay, az, aw));
}

// ---------------- tiled GEMM with v_dot2_f32_f16 ----------------
template <int KT, int RPT, int TN>
__global__ __launch_bounds__(256) void gemm_tiled(
    const __half* __restrict__ A, const float* __restrict__ W,
    const float* __restrict__ rowScaleIn,   // null -> 1
    const float* __restrict__ rowScaleOut,  // null -> no scale/bias
    const float* __restrict__ bias,
    __half* __restrict__ C, int N, int K1, int relu)
{
    constexpr int NC8 = TN / 8;
    constexpr int RT  = 256 / NC8;
    constexpr int TM  = RT * RPT;
    constexpr int AFPT = TM * KT / 256;
    constexpr int KP  = KT / 2;
    static_assert(AFPT == 2 || AFPT == 8, "unexpected AFPT");

    __shared__ h2v Alds[KP][TM];
    __shared__ h2v Wlds[KP][TN];

    const int t    = threadIdx.x;
    const int cg   = t % NC8;
    const int rt   = t / NC8;
    const int c0   = cg * 8;
    const int row0 = blockIdx.x * TM;

    const int arow   = t % TM;
    const int akb    = (t / TM) * AFPT;
    const int arow_g = row0 + arow;
    float rsc = 1.0f;
    if (rowScaleIn && arow_g < N) rsc = rowScaleIn[arow_g];

    float acc[RPT][8];
#pragma unroll
    for (int r = 0; r < RPT; ++r)
#pragma unroll
        for (int j = 0; j < 8; ++j) acc[r][j] = 0.f;

    for (int k0 = 0; k0 < K1; k0 += KT) {
        float av[AFPT];
        if (arow_g < N) {
            const __half* ag = A + (size_t)arow_g * K1 + k0 + akb;
            if constexpr (AFPT == 8) ld8v(ag, av);
            else                     ld2v(ag, av);
        } else {
#pragma unroll
            for (int j = 0; j < AFPT; ++j) av[j] = 0.f;
        }
#pragma unroll
        for (int j = 0; j < AFPT; j += 2)
            Alds[(akb + j) >> 1][arow] = packh2(av[j] * rsc, av[j + 1] * rsc);

        for (int i = t; i < KP * TN; i += 256) {
            int kp = i / TN, c = i % TN;
            Wlds[kp][c] = packh2(W[(size_t)(k0 + 2 * kp) * TN + c],
                                 W[(size_t)(k0 + 2 * kp + 1) * TN + c]);
        }
        __syncthreads();

#pragma unroll
        for (int kp = 0; kp < KP; ++kp) {
            h2v a2[RPT];
            if constexpr (RPT == 4) {
                union { float4 f; h2v h[4]; } u;
                u.f = *(const float4*)&Alds[kp][rt * 4];
                a2[0] = u.h[0]; a2[1] = u.h[1]; a2[2] = u.h[2]; a2[3] = u.h[3];
            } else if constexpr (RPT == 2) {
                union { float2 f; h2v h[2]; } u;
                u.f = *(const float2*)&Alds[kp][rt * 2];
                a2[0] = u.h[0]; a2[1] = u.h[1];
            } else {
                a2[0] = Alds[kp][rt];
            }
            union { float4 f; h2v h[4]; } w0, w1;
            w0.f = *(const float4*)&Wlds[kp][c0];
            w1.f = *(const float4*)&Wlds[kp][c0 + 4];
#pragma unroll
            for (int r = 0; r < RPT; ++r) {
                acc[r][0] = __builtin_amdgcn_fdot2(a2[r], w0.h[0], acc[r][0], false);
                acc[r][1] = __builtin_amdgcn_fdot2(a2[r], w0.h[1], acc[r][1], false);
                acc[r][2] = __builtin_amdgcn_fdot2(a2[r], w0.h[2], acc[r][2], false);
                acc[r][3] = __builtin_amdgcn_fdot2(a2[r], w0.h[3], acc[r][3], false);
                acc[r][4] = __builtin_amdgcn_fdot2(a2[r], w1.h[0], acc[r][4], false);
                acc[r][5] = __builtin_amdgcn_fdot2(a2[r], w1.h[1], acc[r][5], false);
                acc[r][6] = __builtin_amdgcn_fdot2(a2[r], w1.h[2], acc[r][6], false);
                acc[r][7] = __builtin_amdgcn_fdot2(a2[r], w1.h[3], acc[r][7], false);
            }
        }
        __syncthreads();
    }

#pragma unroll
    for (int r = 0; r < RPT; ++r) {
        int row_g = row0 + rt * RPT + r;
        if (row_g >= N) continue;
        float f[8];
        if (rowScaleOut) {
            float sc = rowScaleOut[row_g];
#pragma unroll
            for (int j = 0; j < 8; ++j) f[j] = acc[r][j] * sc + bias[c0 + j];
        } else {
#pragma unroll
            for (int j = 0; j < 8; ++j) f[j] = acc[r][j];
        }
        if (relu) {
#pragma unroll
            for (int j = 0; j < 8; ++j) f[j] = fmaxf(f[j], 0.f);
        }
        st8f(C + (size_t)row_g * TN + c0, f);
    }
}

static inline int nblk(long n) { return (int)((n + BLOCK - 1) / BLOCK); }

extern "C" void kernel_launch(void* const* d_in, const int* in_sizes, int n_in,
                              void* d_out, int out_size, void* d_ws, size_t ws_size,
                              hipStream_t stream) {
    const float* x    = (const float*)d_in[0];
    const float* efet = (const float*)d_in[1];
    const int*   src  = (const int*)d_in[2];
    const int*   dst  = (const int*)d_in[3];
    const float* W1 = (const float*)d_in[4];  const float* b1 = (const float*)d_in[5];
    const float* W2 = (const float*)d_in[6];  const float* b2 = (const float*)d_in[7];
    const float* W3 = (const float*)d_in[8];  const float* b3 = (const float*)d_in[9];
    const float* W4 = (const float*)d_in[10]; const float* b4 = (const float*)d_in[11];
    const float* W5 = (const float*)d_in[12]; const float* b5 = (const float*)d_in[13];
    float* out = (float*)d_out;

    const int N = in_sizes[0] / 16;
    const int E = in_sizes[2];
    const int NBUK = (N + 127) / 128;
    const int T = (E + 3) / 4;

    // ---- workspace layout (4B units, 16B-aligned chunks) ----
    float* fws = (float*)d_ws;
    size_t o = 0;
    auto alloc = [&](size_t nf) { float* p = fws + o; o += (nf + 3) & ~(size_t)3; return p; };
    float*  normO     = alloc(N);
    float*  normI     = alloc(N);
    int2*   rowSpan   = (int2*)alloc(2 * (size_t)N);
    int2*   edges     = (int2*)alloc(2 * (size_t)E);
    // --- contiguous zeroed region: degO_x, scur, ovcur, gcur ---
    int*    degO_x    = (int*)alloc(8 * (size_t)N);
    int*    scur      = (int*)alloc((size_t)NBUK * 8 * PAD);
    int*    ovcur     = (int*)alloc((size_t)NBUK * PAD);
    int*    gcur      = (int*)alloc(4);
    size_t zeroBytes  = (8 * (size_t)N + (size_t)NBUK * 8 * PAD + (size_t)NBUK * PAD + 4) * 4;
    int2*   staging   = (int2*)alloc(2 * (size_t)NBUK * 8 * SUBCAP);
    int2*   overflow  = (int2*)alloc(2 * (size_t)NBUK * OVCAP);
    __half* xh        = (__half*)alloc(8 * (size_t)N);
    __half* bufA      = (__half*)alloc(128 * (size_t)N);
    __half* bufB      = (__half*)alloc(128 * (size_t)N);
    __half* bufC      = (__half*)alloc(64 * (size_t)N);
    float*  t5f       = (float*)bufB;                    // layer-5 fp32 temp (m4 lives in bufA)

    // ---- CSR build: binA -> binB (binB also does normO + x->fp16) ----
    hipMemsetAsync(degO_x, 0, zeroBytes, stream);
    binA_kernel<<<nblk(T), BLOCK, 0, stream>>>(src, dst, efet, degO_x,
                                               scur, ovcur, staging, overflow, N, E, T);
    binB_kernel<<<NBUK, 256, 0, stream>>>(scur, ovcur, staging, overflow,
                                          gcur, rowSpan, normI, edges,
                                          degO_x, x, xh, normO, N);

    // ---- Layer 1: agg16 -> GEMM 16->256 -> ewa256 ----
    agg8_kernel<16><<<nblk((long)N * 2), BLOCK, 0, stream>>>(
        xh, bufC, rowSpan, edges, 0, nullptr, nullptr, N, 0);
    gemm_tiled<16, 4, 256><<<(N + 31) / 32, 256, 0, stream>>>(
        bufC, W1, nullptr, normI, b1, bufA, N, 16, 1);
    agg8_kernel<256><<<nblk((long)N * 32), BLOCK, 0, stream>>>(
        bufA, bufB, rowSpan, edges, 1, nullptr, nullptr, N, 1);   // h1 = bufB

    // ---- Layer 2: GEMM 256->128, gc128, ewa128 ----
    gemm_tiled<32, 4, 128><<<(N + 63) / 64, 256, 0, stream>>>(
        bufB, W2, normO, nullptr, nullptr, bufA, N, 256, 0);
    agg8_kernel<128><<<nblk((long)N * 16), BLOCK, 0, stream>>>(
        bufA, bufC, rowSpan, edges, 0, normI, b2, N, 1);
    agg8_kernel<128><<<nblk((long)N * 16), BLOCK, 0, stream>>>(
        bufC, bufB, rowSpan, edges, 1, nullptr, nullptr, N, 1);   // h2 = bufB

    // ---- Layer 3: GEMM 128->64, gc64, ewa64 ----
    gemm_tiled<32, 2, 64><<<(N + 63) / 64, 256, 0, stream>>>(
        bufB, W3, normO, nullptr, nullptr, bufA, N, 128, 0);
    agg8_kernel<64><<<nblk((long)N * 8), BLOCK, 0, stream>>>(
        bufA, bufC, rowSpan, edges, 0, normI, b3, N, 1);
    agg8_kernel<64><<<nblk((long)N * 8), BLOCK, 0, stream>>>(
        bufC, bufB, rowSpan, edges, 1, nullptr, nullptr, N, 1);   // h3 = bufB

    // ---- Layer 4: GEMM 64->32 -> m4 (bufA), gc32 fused w/ 32->4 GEMM -> t5f (bufB) ----
    gemm_tiled<32, 1, 32><<<(N + 63) / 64, 256, 0, stream>>>(
        bufB, W4, normO, nullptr, nullptr, bufA, N, 64, 0);
    gc32_fused<<<nblk((long)N * 4), BLOCK, 0, stream>>>(
        bufA, t5f, rowSpan, edges, normI, b4, normO, W5, N);

    // ---- Layer 5: agg4 -> out ----
    agg4_kernel<<<nblk((long)N), BLOCK, 0, stream>>>(
        t5f, out, rowSpan, edges, normI, b5, N);
}

// Round 19
// 466.863 us; speedup vs baseline: 1.0089x; 1.0089x over previous
//
#include <hip/hip_runtime.h>
#include <hip/hip_fp16.h>

#define BLOCK 256
#define PAD 16        // one counter per 64B cache line
#define SUBCAP 512    // staging capacity per (bucket, xcd)
#define OVCAP 4096    // overflow capacity per bucket
#define BUFCAP 4352   // binB LDS record capacity

typedef _Float16 h2v __attribute__((ext_vector_type(2)));

#if defined(__has_builtin) && __has_builtin(__builtin_amdgcn_sched_barrier)
#define SCHED_FENCE() __builtin_amdgcn_sched_barrier(0)
#else
#define SCHED_FENCE()
#endif

// ---------------- helpers ----------------
__device__ inline void st4f(__half* p, float4 v) {
    __half2 a = __floats2half2_rn(v.x, v.y);
    __half2 b = __floats2half2_rn(v.z, v.w);
    uint2 u;
    u.x = *reinterpret_cast<unsigned*>(&a);
    u.y = *reinterpret_cast<unsigned*>(&b);
    *(uint2*)p = u;
}
__device__ inline void st4f(float* p, float4 v) { *(float4*)p = v; }
__device__ inline void st8f(float* p, const float f[8]) {
    *(float4*)p       = make_float4(f[0], f[1], f[2], f[3]);
    *(float4*)(p + 4) = make_float4(f[4], f[5], f[6], f[7]);
}
__device__ inline void st8f(__half* p, const float f[8]) {
    union { __half2 h[4]; float4 v; } u;
    u.h[0] = __floats2half2_rn(f[0], f[1]);
    u.h[1] = __floats2half2_rn(f[2], f[3]);
    u.h[2] = __floats2half2_rn(f[4], f[5]);
    u.h[3] = __floats2half2_rn(f[6], f[7]);
    *(float4*)p = u.v;
}
__device__ inline void ld2v(const __half* p, float* f) {
    float2 v = __half22float2(*(const __half2*)p); f[0] = v.x; f[1] = v.y;
}
__device__ inline void ld8v(const __half* p, float* f) {
    float4 r = *(const float4*)p;
    const __half2* h = (const __half2*)&r;
#pragma unroll
    for (int j = 0; j < 4; ++j) {
        float2 fj = __half22float2(h[j]);
        f[2*j] = fj.x; f[2*j+1] = fj.y;
    }
}
__device__ inline float4 ld4f(const float* p) { return *(const float4*)p; }
__device__ inline float edgeW(int2 er) {
    return __half2float(__ushort_as_half((unsigned short)(er.y & 0xffff)));
}
__device__ inline h2v packh2(float a, float b) {
    h2v r; r.x = (_Float16)a; r.y = (_Float16)b; return r;
}
// non-temporal 8B record load (int2 via long long bit-cast)
__device__ inline int2 ntld2(const int2* p) {
    long long v = __builtin_nontemporal_load((const long long*)p);
    union { long long l; int2 i; } u; u.l = v; return u.i;
}

// ---------------- binA: 1 edge/thread, NON-TEMPORAL edge-stream reads ----------------
// Streaming src/dst/efet reads are marked non-temporal so they don't evict the
// partially-filled staging lines from L2 (the cause of the 9x write blowup).
// XCC_ID is a locality hint only; binB drains all sub-regions + overflow.
__global__ void binA_kernel(const int* __restrict__ src, const int* __restrict__ dst,
                            const float* __restrict__ efet,
                            int* __restrict__ degO_x,
                            int* __restrict__ scur, int* __restrict__ ovcur,
                            int2* __restrict__ staging, int2* __restrict__ overflow,
                            int N, int E) {
    int e = blockIdx.x * blockDim.x + threadIdx.x;
    if (e >= E) return;
    int s = __builtin_nontemporal_load(src + e);
    int d = __builtin_nontemporal_load(dst + e);
    float w = __builtin_nontemporal_load(efet + e);
    int xcc = __builtin_amdgcn_s_getreg(63508) & 7;   // hwreg(XCC_ID,0,32)
    atomicAdd(&degO_x[(size_t)xcc * N + s], 1);       // XCD-local line, fire & forget
    int b = d >> 7;
    int2 rec;
    rec.x = s;
    rec.y = (int)__half_as_ushort(__float2half(w)) | ((d & 127) << 16);
    int slot = b * 8 + xcc;
    int p = atomicAdd(&scur[slot * PAD], 1);
    if (p < SUBCAP) {
        staging[(size_t)slot * SUBCAP + p] = rec;
    } else {
        int q = atomicAdd(&ovcur[b * PAD], 1);
        if (q < OVCAP) overflow[(size_t)b * OVCAP + q] = rec;
    }
}

// ---------------- binB: bucket drain -> LDS -> count/scan/ticket -> rowSpan+edges
//                   + normO/xh conversion for the bucket's nodes ----------------
__global__ __launch_bounds__(256) void binB_kernel(
    const int* __restrict__ scur, const int* __restrict__ ovcur,
    const int2* __restrict__ staging, const int2* __restrict__ overflow,
    int* __restrict__ gcur, int2* __restrict__ rowSpan, float* __restrict__ normI,
    int2* __restrict__ edges,
    const int* __restrict__ degO_x, const float* __restrict__ x,
    __half* __restrict__ xh, float* __restrict__ normO, int N) {
    __shared__ int2 buf[BUFCAP];
    __shared__ int cnt[128];
    __shared__ int rs[128];
    __shared__ int cur[128];
    __shared__ float nO[128];
    __shared__ int base;
    int b = blockIdx.x;
    int v0 = b << 7;
    int t = threadIdx.x;
    int nn = N - v0; if (nn > 128) nn = 128;
    if (t < 128) cnt[t] = 0;

    // region offsets (computed identically by all threads)
    int offs[8], acc = 0;
#pragma unroll
    for (int r = 0; r < 8; ++r) {
        int c = scur[(b * 8 + r) * PAD];
        if (c > SUBCAP) c = SUBCAP;
        offs[r] = acc; acc += c;
    }
    int oc = ovcur[b * PAD];
    if (oc > OVCAP) oc = OVCAP;
    int total = acc + oc;
    if (total > BUFCAP) total = BUFCAP;
    __syncthreads();

    // drain staging + overflow into LDS (read-once -> non-temporal)
#pragma unroll
    for (int r = 0; r < 8; ++r) {
        int c = (r < 7 ? offs[r + 1] : acc) - offs[r];
        const int2* reg = staging + (size_t)(b * 8 + r) * SUBCAP;
        for (int i = t; i < c; i += 256) {
            int o = offs[r] + i;
            if (o < BUFCAP) buf[o] = ntld2(reg + i);
        }
    }
    {
        const int2* reg = overflow + (size_t)b * OVCAP;
        for (int i = t; i < oc; i += 256) {
            int o = acc + i;
            if (o < BUFCAP) buf[o] = ntld2(reg + i);
        }
    }
    __syncthreads();

    // count per-node
    for (int i = t; i < total; i += 256)
        atomicAdd(&cnt[(buf[i].y >> 16) & 127], 1);
    __syncthreads();

    if (t == 0) {
        base = atomicAdd(gcur, total);
        int a2 = 0;
        for (int k = 0; k < 128; ++k) { rs[k] = a2; a2 += cnt[k]; }
    }
    __syncthreads();

    if (t < 128) {
        cur[t] = 0;
        int v = v0 + t;
        if (v < N) {
            int2 sp;
            sp.x = base + rs[t];
            sp.y = sp.x + cnt[t];
            rowSpan[v] = sp;
            normI[v] = rsqrtf(fmaxf((float)cnt[t], 1.0f));
            int dsum = 0;
#pragma unroll
            for (int k = 0; k < 8; ++k) dsum += degO_x[(size_t)k * N + v];
            float wv = rsqrtf(fmaxf((float)dsum, 1.0f));
            nO[t] = wv;
            normO[v] = wv;
        }
    }
    __syncthreads();

    // scatter LDS -> contiguous bucket span of edges
    for (int i = t; i < total; i += 256) {
        int2 rec = buf[i];
        int dl = (rec.y >> 16) & 127;
        int lp = atomicAdd(&cur[dl], 1);
        edges[base + rs[dl] + lp] = rec;
    }

    // x -> fp16 with normO folded, for this bucket's nodes
    for (int i = t; i < nn * 4; i += 256) {
        int vl = i >> 2, c = (i & 3) * 4;
        int v = v0 + vl;
        float4 f = ld4f(x + (size_t)v * 16 + c);
        float wv = nO[vl];
        f.x *= wv; f.y *= wv; f.z *= wv; f.w *= wv;
        st4f(xh + (size_t)v * 16 + c, f);
    }
}

// ---------------- CSR gather-agg, 8 cols/thread, sched-fenced batched loads ---------
template <int D>
__global__ __launch_bounds__(256) void agg8_kernel(
    const __half* __restrict__ in, __half* __restrict__ out,
    const int2* __restrict__ rowSpan, const int2* __restrict__ edges,
    int useW,
    const float* __restrict__ dstScale,   // null -> skip scale+bias
    const float* __restrict__ bias,
    int N, int relu) {
    constexpr int TPN = D / 8;
    int gid = blockIdx.x * blockDim.x + threadIdx.x;
    int v = gid / TPN;
    int c8 = (gid % TPN) * 8;
    if (v >= N) return;
    int2 sp = rowSpan[v];
    int beg = sp.x, end = sp.y;
    float a[8];
#pragma unroll
    for (int k = 0; k < 8; ++k) a[k] = 0.f;
    const __half* base = in + c8;

    int j = beg;
    for (; j + 8 <= end; j += 8) {
        int2 er[8];
#pragma unroll
        for (int q = 0; q < 8; ++q) er[q] = edges[j + q];
        SCHED_FENCE();
        float4 raw[8];
#pragma unroll
        for (int q = 0; q < 8; ++q) raw[q] = *(const float4*)(base + (size_t)er[q].x * D);
        SCHED_FENCE();
#pragma unroll
        for (int q = 0; q < 8; ++q) {
            float w = useW ? edgeW(er[q]) : 1.f;
            const __half2* h = (const __half2*)&raw[q];
#pragma unroll
            for (int p = 0; p < 4; ++p) {
                float2 fj = __half22float2(h[p]);
                a[2*p]   += fj.x * w;
                a[2*p+1] += fj.y * w;
            }
        }
    }
    if (j + 4 <= end) {
        int2 er[4];
#pragma unroll
        for (int q = 0; q < 4; ++q) er[q] = edges[j + q];
        SCHED_FENCE();
        float4 raw[4];
#pragma unroll
        for (int q = 0; q < 4; ++q) raw[q] = *(const float4*)(base + (size_t)er[q].x * D);
        SCHED_FENCE();
#pragma unroll
        for (int q = 0; q < 4; ++q) {
            float w = useW ? edgeW(er[q]) : 1.f;
            const __half2* h = (const __half2*)&raw[q];
#pragma unroll
            for (int p = 0; p < 4; ++p) {
                float2 fj = __half22float2(h[p]);
                a[2*p]   += fj.x * w;
                a[2*p+1] += fj.y * w;
            }
        }
        j += 4;
    }
    for (; j < end; ++j) {
        int2 er = edges[j];
        float w = useW ? edgeW(er) : 1.f;
        float xv[8];
        ld8v(base + (size_t)er.x * D, xv);
#pragma unroll
        for (int k = 0; k < 8; ++k) a[k] += xv[k] * w;
    }
    if (dstScale) {
        float sc = dstScale[v];
#pragma unroll
        for (int k = 0; k < 8; ++k) a[k] = a[k] * sc + bias[c8 + k];
    }
    if (relu) {
#pragma unroll
        for (int k = 0; k < 8; ++k) a[k] = fmaxf(a[k], 0.f);
    }
    st8f(out + (size_t)v * D + c8, a);
}

// ---------------- gc32 fused with 32->4 GEMM (W5) ----------------
__global__ __launch_bounds__(256) void gc32_fused(
    const __half* __restrict__ in, float* __restrict__ t5,
    const int2* __restrict__ rowSpan, const int2* __restrict__ edges,
    const float* __restrict__ normI, const float* __restrict__ b4,
    const float* __restrict__ normO, const float* __restrict__ W5,
    int N) {
    int gid = blockIdx.x * blockDim.x + threadIdx.x;
    int v = gid >> 2;
    int q = gid & 3;
    int c8 = q * 8;
    if (v >= N) return;
    int2 sp = rowSpan[v];
    int beg = sp.x, end = sp.y;
    float a[8];
#pragma unroll
    for (int k = 0; k < 8; ++k) a[k] = 0.f;
    const __half* base = in + c8;

    int j = beg;
    for (; j + 8 <= end; j += 8) {
        int2 er[8];
#pragma unroll
        for (int p = 0; p < 8; ++p) er[p] = edges[j + p];
        SCHED_FENCE();
        float4 raw[8];
#pragma unroll
        for (int p = 0; p < 8; ++p) raw[p] = *(const float4*)(base + (size_t)er[p].x * 32);
        SCHED_FENCE();
#pragma unroll
        for (int p = 0; p < 8; ++p) {
            const __half2* h = (const __half2*)&raw[p];
#pragma unroll
            for (int s = 0; s < 4; ++s) {
                float2 fj = __half22float2(h[s]);
                a[2*s]   += fj.x;
                a[2*s+1] += fj.y;
            }
        }
    }
    for (; j < end; ++j) {
        int2 er = edges[j];
        float xv[8];
        ld8v(base + (size_t)er.x * 32, xv);
#pragma unroll
        for (int k = 0; k < 8; ++k) a[k] += xv[k];
    }
    float sc = normI[v];
#pragma unroll
    for (int k = 0; k < 8; ++k) a[k] = fmaxf(a[k] * sc + b4[c8 + k], 0.f);

    float p4[4] = {0.f, 0.f, 0.f, 0.f};
#pragma unroll
    for (int k = 0; k < 8; ++k) {
        float4 wr = ld4f(W5 + (size_t)(c8 + k) * 4);
        p4[0] += a[k] * wr.x; p4[1] += a[k] * wr.y;
        p4[2] += a[k] * wr.z; p4[3] += a[k] * wr.w;
    }
#pragma unroll
    for (int c = 0; c < 4; ++c) {
        p4[c] += __shfl_xor(p4[c], 1);
        p4[c] += __shfl_xor(p4[c], 2);
    }
    if (q == 0) {
        float no = normO[v];
        st4f(t5 + (size_t)v * 4, make_float4(p4[0]*no, p4[1]*no, p4[2]*no, p4[3]*no));
    }
}

// ---------------- final agg: D=4, fp32, batched loads ----------------
__global__ void agg4_kernel(const float* __restrict__ in, float* __restrict__ out,
                            const int2* __restrict__ rowSpan, const int2* __restrict__ edges,
                            const float* __restrict__ dstScale, const float* __restrict__ bias,
                            int N) {
    int v = blockIdx.x * blockDim.x + threadIdx.x;
    if (v >= N) return;
    int2 sp = rowSpan[v];
    int beg = sp.x, end = sp.y;
    float ax = 0.f, ay = 0.f, az = 0.f, aw = 0.f;
    int j = beg;
    for (; j + 4 <= end; j += 4) {
        int2 er[4];
#pragma unroll
        for (int q = 0; q < 4; ++q) er[q] = edges[j + q];
        SCHED_FENCE();
        float4 raw[4];
#pragma unroll
        for (int q = 0; q < 4; ++q) raw[q] = ld4f(in + (size_t)er[q].x * 4);
        SCHED_FENCE();
#pragma unroll
        for (int q = 0; q < 4; ++q) {
            ax += raw[q].x; ay += raw[q].y; az += raw[q].z; aw += raw[q].w;
        }
    }
    for (; j < end; ++j) {
        float4 val = ld4f(in + (size_t)edges[j].x * 4);
        ax += val.x; ay += val.y; az += val.z; aw += val.w;
    }
    float sc = dstScale[v];
    ax = ax * sc + bias[0];
    ay = ay * sc + bias[1];
    az = az * sc + bias[2];
    aw = aw * sc + bias[3];
    st4f(out + (size_t)v * 4, make_float4(ax, ay, az, aw));
}

// ---------------- tiled GEMM with v_dot2_f32_f16 ----------------
template <int KT, int RPT, int TN>
__global__ __launch_bounds__(256) void gemm_tiled(
    const __half* __restrict__ A, const float* __restrict__ W,
    const float* __restrict__ rowScaleIn,   // null -> 1
    const float* __restrict__ rowScaleOut,  // null -> no scale/bias
    const float* __restrict__ bias,
    __half* __restrict__ C, int N, int K1, int relu)
{
    constexpr int NC8 = TN / 8;
    constexpr int RT  = 256 / NC8;
    constexpr int TM  = RT * RPT;
    constexpr int AFPT = TM * KT / 256;
    constexpr int KP  = KT / 2;
    static_assert(AFPT == 2 || AFPT == 8, "unexpected AFPT");

    __shared__ h2v Alds[KP][TM];
    __shared__ h2v Wlds[KP][TN];

    const int t    = threadIdx.x;
    const int cg   = t % NC8;
    const int rt   = t / NC8;
    const int c0   = cg * 8;
    const int row0 = blockIdx.x * TM;

    const int arow   = t % TM;
    const int akb    = (t / TM) * AFPT;
    const int arow_g = row0 + arow;
    float rsc = 1.0f;
    if (rowScaleIn && arow_g < N) rsc = rowScaleIn[arow_g];

    float acc[RPT][8];
#pragma unroll
    for (int r = 0; r < RPT; ++r)
#pragma unroll
        for (int j = 0; j < 8; ++j) acc[r][j] = 0.f;

    for (int k0 = 0; k0 < K1; k0 += KT) {
        float av[AFPT];
        if (arow_g < N) {
            const __half* ag = A + (size_t)arow_g * K1 + k0 + akb;
            if constexpr (AFPT == 8) ld8v(ag, av);
            else                     ld2v(ag, av);
        } else {
#pragma unroll
            for (int j = 0; j < AFPT; ++j) av[j] = 0.f;
        }
#pragma unroll
        for (int j = 0; j < AFPT; j += 2)
            Alds[(akb + j) >> 1][arow] = packh2(av[j] * rsc, av[j + 1] * rsc);

        for (int i = t; i < KP * TN; i += 256) {
            int kp = i / TN, c = i % TN;
            Wlds[kp][c] = packh2(W[(size_t)(k0 + 2 * kp) * TN + c],
                                 W[(size_t)(k0 + 2 * kp + 1) * TN + c]);
        }
        __syncthreads();

#pragma unroll
        for (int kp = 0; kp < KP; ++kp) {
            h2v a2[RPT];
            if constexpr (RPT == 4) {
                union { float4 f; h2v h[4]; } u;
                u.f = *(const float4*)&Alds[kp][rt * 4];
                a2[0] = u.h[0]; a2[1] = u.h[1]; a2[2] = u.h[2]; a2[3] = u.h[3];
            } else if constexpr (RPT == 2) {
                union { float2 f; h2v h[2]; } u;
                u.f = *(const float2*)&Alds[kp][rt * 2];
                a2[0] = u.h[0]; a2[1] = u.h[1];
            } else {
                a2[0] = Alds[kp][rt];
            }
            union { float4 f; h2v h[4]; } w0, w1;
            w0.f = *(const float4*)&Wlds[kp][c0];
            w1.f = *(const float4*)&Wlds[kp][c0 + 4];
#pragma unroll
            for (int r = 0; r < RPT; ++r) {
                acc[r][0] = __builtin_amdgcn_fdot2(a2[r], w0.h[0], acc[r][0], false);
                acc[r][1] = __builtin_amdgcn_fdot2(a2[r], w0.h[1], acc[r][1], false);
                acc[r][2] = __builtin_amdgcn_fdot2(a2[r], w0.h[2], acc[r][2], false);
                acc[r][3] = __builtin_amdgcn_fdot2(a2[r], w0.h[3], acc[r][3], false);
                acc[r][4] = __builtin_amdgcn_fdot2(a2[r], w1.h[0], acc[r][4], false);
                acc[r][5] = __builtin_amdgcn_fdot2(a2[r], w1.h[1], acc[r][5], false);
                acc[r][6] = __builtin_amdgcn_fdot2(a2[r], w1.h[2], acc[r][6], false);
                acc[r][7] = __builtin_amdgcn_fdot2(a2[r], w1.h[3], acc[r][7], false);
            }
        }
        __syncthreads();
    }

#pragma unroll
    for (int r = 0; r < RPT; ++r) {
        int row_g = row0 + rt * RPT + r;
        if (row_g >= N) continue;
        float f[8];
        if (rowScaleOut) {
            float sc = rowScaleOut[row_g];
#pragma unroll
            for (int j = 0; j < 8; ++j) f[j] = acc[r][j] * sc + bias[c0 + j];
        } else {
#pragma unroll
            for (int j = 0; j < 8; ++j) f[j] = acc[r][j];
        }
        if (relu) {
#pragma unroll
            for (int j = 0; j < 8; ++j) f[j] = fmaxf(f[j], 0.f);
        }
        st8f(C + (size_t)row_g * TN + c0, f);
    }
}

static inline int nblk(long n) { return (int)((n + BLOCK - 1) / BLOCK); }

extern "C" void kernel_launch(void* const* d_in, const int* in_sizes, int n_in,
                              void* d_out, int out_size, void* d_ws, size_t ws_size,
                              hipStream_t stream) {
    const float* x    = (const float*)d_in[0];
    const float* efet = (const float*)d_in[1];
    const int*   src  = (const int*)d_in[2];
    const int*   dst  = (const int*)d_in[3];
    const float* W1 = (const float*)d_in[4];  const float* b1 = (const float*)d_in[5];
    const float* W2 = (const float*)d_in[6];  const float* b2 = (const float*)d_in[7];
    const float* W3 = (const float*)d_in[8];  const float* b3 = (const float*)d_in[9];
    const float* W4 = (const float*)d_in[10]; const float* b4 = (const float*)d_in[11];
    const float* W5 = (const float*)d_in[12]; const float* b5 = (const float*)d_in[13];
    float* out = (float*)d_out;

    const int N = in_sizes[0] / 16;
    const int E = in_sizes[2];
    const int NBUK = (N + 127) / 128;

    // ---- workspace layout (4B units, 16B-aligned chunks) ----
    float* fws = (float*)d_ws;
    size_t o = 0;
    auto alloc = [&](size_t nf) { float* p = fws + o; o += (nf + 3) & ~(size_t)3; return p; };
    float*  normO     = alloc(N);
    float*  normI     = alloc(N);
    int2*   rowSpan   = (int2*)alloc(2 * (size_t)N);
    int2*   edges     = (int2*)alloc(2 * (size_t)E);
    // --- contiguous zeroed region: degO_x, scur, ovcur, gcur ---
    int*    degO_x    = (int*)alloc(8 * (size_t)N);
    int*    scur      = (int*)alloc((size_t)NBUK * 8 * PAD);
    int*    ovcur     = (int*)alloc((size_t)NBUK * PAD);
    int*    gcur      = (int*)alloc(4);
    size_t zeroBytes  = (8 * (size_t)N + (size_t)NBUK * 8 * PAD + (size_t)NBUK * PAD + 4) * 4;
    int2*   staging   = (int2*)alloc(2 * (size_t)NBUK * 8 * SUBCAP);
    int2*   overflow  = (int2*)alloc(2 * (size_t)NBUK * OVCAP);
    __half* xh        = (__half*)alloc(8 * (size_t)N);
    __half* bufA      = (__half*)alloc(128 * (size_t)N);
    __half* bufB      = (__half*)alloc(128 * (size_t)N);
    __half* bufC      = (__half*)alloc(64 * (size_t)N);
    float*  t5f       = (float*)bufB;                    // layer-5 fp32 temp (m4 lives in bufA)

    // ---- CSR build: binA -> binB (binB also does normO + x->fp16) ----
    hipMemsetAsync(degO_x, 0, zeroBytes, stream);
    binA_kernel<<<nblk(E), BLOCK, 0, stream>>>(src, dst, efet, degO_x,
                                               scur, ovcur, staging, overflow, N, E);
    binB_kernel<<<NBUK, 256, 0, stream>>>(scur, ovcur, staging, overflow,
                                          gcur, rowSpan, normI, edges,
                                          degO_x, x, xh, normO, N);

    // ---- Layer 1: agg16 -> GEMM 16->256 -> ewa256 ----
    agg8_kernel<16><<<nblk((long)N * 2), BLOCK, 0, stream>>>(
        xh, bufC, rowSpan, edges, 0, nullptr, nullptr, N, 0);
    gemm_tiled<16, 4, 256><<<(N + 31) / 32, 256, 0, stream>>>(
        bufC, W1, nullptr, normI, b1, bufA, N, 16, 1);
    agg8_kernel<256><<<nblk((long)N * 32), BLOCK, 0, stream>>>(
        bufA, bufB, rowSpan, edges, 1, nullptr, nullptr, N, 1);   // h1 = bufB

    // ---- Layer 2: GEMM 256->128, gc128, ewa128 ----
    gemm_tiled<32, 4, 128><<<(N + 63) / 64, 256, 0, stream>>>(
        bufB, W2, normO, nullptr, nullptr, bufA, N, 256, 0);
    agg8_kernel<128><<<nblk((long)N * 16), BLOCK, 0, stream>>>(
        bufA, bufC, rowSpan, edges, 0, normI, b2, N, 1);
    agg8_kernel<128><<<nblk((long)N * 16), BLOCK, 0, stream>>>(
        bufC, bufB, rowSpan, edges, 1, nullptr, nullptr, N, 1);   // h2 = bufB

    // ---- Layer 3: GEMM 128->64, gc64, ewa64 ----
    gemm_tiled<32, 2, 64><<<(N + 63) / 64, 256, 0, stream>>>(
        bufB, W3, normO, nullptr, nullptr, bufA, N, 128, 0);
    agg8_kernel<64><<<nblk((long)N * 8), BLOCK, 0, stream>>>(
        bufA, bufC, rowSpan, edges, 0, normI, b3, N, 1);
    agg8_kernel<64><<<nblk((long)N * 8), BLOCK, 0, stream>>>(
        bufC, bufB, rowSpan, edges, 1, nullptr, nullptr, N, 1);   // h3 = bufB

    // ---- Layer 4: GEMM 64->32 -> m4 (bufA), gc32 fused w/ 32->4 GEMM -> t5f (bufB) ----
    gemm_tiled<32, 1, 32><<<(N + 63) / 64, 256, 0, stream>>>(
        bufB, W4, normO, nullptr, nullptr, bufA, N, 64, 0);
    gc32_fused<<<nblk((long)N * 4), BLOCK, 0, stream>>>(
        bufA, t5f, rowSpan, edges, normI, b4, normO, W5, N);

    // ---- Layer 5: agg4 -> out ----
    agg4_kernel<<<nblk((long)N), BLOCK, 0, stream>>>(
        t5f, out, rowSpan, edges, normI, b5, N);
}